// Round 18
// baseline (61.650 us; speedup 1.0000x reference)
//
#include <hip/hip_runtime.h>
#include <hip/hip_bf16.h>

// Problem dims
#define B_ 8
#define S_ 2048
#define C_ 128
#define H_ 4
#define D_ 32
#define SC_ (S_*C_)      // 262144 elements per batch
#define HD_ (H_*D_)      // 128

typedef short bf16x8 __attribute__((ext_vector_type(8)));
typedef float f32x4 __attribute__((ext_vector_type(4)));
union FragU { uint4 u; bf16x8 h; };

// ---------- bf16 helpers ----------
__device__ __forceinline__ unsigned short f2bf(float f) {
  __hip_bfloat16 h = __float2bfloat16(f);   // RNE
  return *reinterpret_cast<unsigned short*>(&h);
}
// truncation pack via byte-perm: {hi16(b), hi16(a)} in ONE v_perm_b32.
// P>0 and the SAME values feed numerator and denominator -> bias cancels.
__device__ __forceinline__ unsigned int pk2t(float a, float b) {
  union { float f; unsigned int u; } ua, ub;
  ua.f = a; ub.f = b;
  return __builtin_amdgcn_perm(ub.u, ua.u, 0x07060302u);
}
// RNE pack (for V staging - bias must not accumulate in PV numerator)
__device__ __forceinline__ unsigned int pk2r(float a, float b) {
  return (unsigned int)f2bf(a) | ((unsigned int)f2bf(b) << 16);
}
#define EXP2(x) __builtin_amdgcn_exp2f(x)

// ---------- K1a: GroupNorm partial sums (256 blocks = 8b x 32 slices) + W->bf16 convert ----------
__global__ __launch_bounds__(256) void k_stats1(const float* __restrict__ x,
                                                const float* __restrict__ wqkv,
                                                const float* __restrict__ wout,
                                                float* __restrict__ part,
                                                unsigned short* __restrict__ wq_bf,
                                                unsigned short* __restrict__ wo_bf) {
  __shared__ float ssum[256], ssq[256];
  int b = blockIdx.x >> 5, sl = blockIdx.x & 31;
  int tid = threadIdx.x;
  // fused one-time weight conversion: 16384 float4 total
  int gid = blockIdx.x * 256 + tid;
  if (gid < 16384) {
    int e = gid * 4;
    const float4 u = (e < 49152) ? *(const float4*)(wqkv + e) : *(const float4*)(wout + e - 49152);
    unsigned short tv[4] = {f2bf(u.x), f2bf(u.y), f2bf(u.z), f2bf(u.w)};
    unsigned short* dst = (e < 49152) ? (wq_bf + e) : (wo_bf + e - 49152);
    *(uint2*)dst = *(uint2*)tv;
  }
  const float4* xp = (const float4*)(x + (size_t)b * SC_);   // 65536 float4 per batch
  float sum = 0.f, sq = 0.f;
  for (int i = sl * 2048 + tid; i < (sl + 1) * 2048; i += 256) {
    float4 u = xp[i];
    sum += u.x + u.y + u.z + u.w;
    sq  += u.x*u.x + u.y*u.y + u.z*u.z + u.w*u.w;
  }
  ssum[tid] = sum; ssq[tid] = sq;
  __syncthreads();
  for (int s = 128; s > 0; s >>= 1) {
    if (tid < s) { ssum[tid] += ssum[tid + s]; ssq[tid] += ssq[tid + s]; }
    __syncthreads();
  }
  if (tid == 0) { part[blockIdx.x * 2] = ssum[0]; part[blockIdx.x * 2 + 1] = ssq[0]; }
}

// ---------- K2: normalize + QKV projection, MFMA; W direct from L2; coalesced V epilogue ----------
__global__ __launch_bounds__(512) void k_qkv(const float* __restrict__ x,
                                             const float* __restrict__ gamma,
                                             const float* __restrict__ beta,
                                             const unsigned short* __restrict__ wq_bf,
                                             const float* __restrict__ part,
                                             unsigned short* __restrict__ q_ws,
                                             unsigned short* __restrict__ k_ws,
                                             unsigned short* __restrict__ v_ws) {
  __shared__ __align__(16) unsigned short Nls[32][136];   // reused as Vbuf[128][32]
  __shared__ float gs[128], bs[128];
  __shared__ float st2[2];
  const int tid = threadIdx.x;
  const int w = tid >> 6, l = tid & 63, g = l >> 4, i = l & 15;
  const int gr0 = blockIdx.x * 32;          // never crosses batch
  const int b = gr0 >> 11;
  if (tid < 128) { gs[tid] = gamma[tid]; bs[tid] = beta[tid]; }
  if (tid < 32) {   // in-block stats reduction
    float s1 = part[(b * 32 + tid) * 2];
    float s2 = part[(b * 32 + tid) * 2 + 1];
    #pragma unroll
    for (int m = 16; m >= 1; m >>= 1) { s1 += __shfl_xor(s1, m); s2 += __shfl_xor(s2, m); }
    if (tid == 0) {
      float mu = s1 / (float)SC_;
      float var = s2 / (float)SC_ - mu * mu;
      st2[0] = mu; st2[1] = rsqrtf(var + 1e-5f);
    }
  }
  __syncthreads();
  const float mu = st2[0], rstd = st2[1];
  {
    const float4* xp = (const float4*)(x + (size_t)gr0 * C_);   // 1024 float4
    #pragma unroll
    for (int t = 0; t < 2; ++t) {
      int e = tid + t * 512;
      float4 u = xp[e];
      int r = e >> 5, c0 = (e & 31) * 4;
      float4 gv = *(const float4*)&gs[c0];
      float4 bv = *(const float4*)&bs[c0];
      unsigned short tv[4] = {
        f2bf((u.x - mu) * rstd * gv.x + bv.x),
        f2bf((u.y - mu) * rstd * gv.y + bv.y),
        f2bf((u.z - mu) * rstd * gv.z + bv.z),
        f2bf((u.w - mu) * rstd * gv.w + bv.w)};
      *(uint2*)&Nls[r][c0] = *(uint2*)tv;
    }
  }
  __syncthreads();
  f32x4 acc[2][3];
  #pragma unroll
  for (int rt = 0; rt < 2; ++rt)
    #pragma unroll
    for (int n = 0; n < 3; ++n) acc[rt][n] = (f32x4){0.f,0.f,0.f,0.f};

  #pragma unroll
  for (int kk = 0; kk < 4; ++kk) {
    FragU bfr[3];
    #pragma unroll
    for (int n = 0; n < 3; ++n)
      bfr[n].u = *(const uint4*)(wq_bf + (size_t)((w * 3 + n) * 16 + i) * 128 + kk * 32 + 8 * g);
    FragU af[2];
    #pragma unroll
    for (int rt = 0; rt < 2; ++rt) af[rt].u = *(const uint4*)&Nls[rt * 16 + i][kk * 32 + 8 * g];
    #pragma unroll
    for (int n = 0; n < 3; ++n)
      #pragma unroll
      for (int rt = 0; rt < 2; ++rt)
        acc[rt][n] = __builtin_amdgcn_mfma_f32_16x16x32_bf16(af[rt].h, bfr[n].h, acc[rt][n], 0, 0, 0);
  }
  __syncthreads();   // Nls reads done -> reuse as Vbuf
  unsigned short (*Vbuf)[32] = (unsigned short(*)[32])&Nls[0][0];   // [fi=f-256][slot 0..31]

  const float SCQ = 0.17677669529663687f * 1.4426950408889634f;  // D^-0.5 * log2(e)
  const int base64 = ((blockIdx.x & 63) >> 1) * 64;   // 64-group base within batch
  const int odd32 = (blockIdx.x & 1) * 32;
  #pragma unroll
  for (int n = 0; n < 3; ++n) {
    int f = (w * 3 + n) * 16 + i;
    int which = f >> 7, fi = f & 127, h = fi >> 5, dd = fi & 31;
    #pragma unroll
    for (int rt = 0; rt < 2; ++rt) {
      if (which == 2) {
        *(unsigned int*)&Vbuf[fi][8 * g + 4 * rt]     = pk2r(acc[rt][n][0], acc[rt][n][1]);
        *(unsigned int*)&Vbuf[fi][8 * g + 4 * rt + 2] = pk2r(acc[rt][n][2], acc[rt][n][3]);
      } else {
        #pragma unroll
        for (int r = 0; r < 4; ++r) {
          int s = (gr0 + rt * 16 + 4 * g + r) & (S_ - 1);
          if (which == 0) {
            q_ws[(((size_t)b * H_ + h) * S_ + s) * D_ + dd] = f2bf(acc[rt][n][r] * SCQ);
          } else {
            k_ws[(((size_t)b * H_ + h) * S_ + s) * D_ + dd] = f2bf(acc[rt][n][r]);
          }
        }
      }
    }
  }
  __syncthreads();
  // cooperative coalesced V store: 128 fi x 32 slots = 512 x 16B
  {
    int fi = tid >> 2, ch = tid & 3;
    int h = fi >> 5, dd = fi & 31;
    uint4 vv = *(const uint4*)&Vbuf[fi][ch * 8];
    *(uint4*)(v_ws + (((size_t)b * H_ + h) * D_ + dd) * S_ + base64 + odd32 + ch * 8) = vv;
  }
}

// ---------- K3: MFMA flash attention; QBLK=128 (32 q/wave), KVBLK=128; XCD-chunked swizzle ----------
// 1D grid 512. wid=(bid&7)*64+(bid>>3): each XCD owns 4 contiguous (b,h) x all 16 q-blocks
// -> 1MB K/V working set per 4MB L2, halved global re-read traffic (QBLK 64->128).
// 4 waves x 32 q (2 Q-frags); staged K/V frags shared by both -> LDS reads/q halved.
// Swapped QK^T, P in-register (v_perm trunc pack), rowsum mfma(P,1), setprio on MFMA.
__global__ __launch_bounds__(256) void k_attn(const unsigned short* __restrict__ qg,
                                              const unsigned short* __restrict__ kg,
                                              const unsigned short* __restrict__ vg,
                                              unsigned short* __restrict__ og) {
  __shared__ __align__(16) unsigned short Kls[2][128][40];
  __shared__ __align__(16) unsigned short Vt[2][32][136];
  const int tid = threadIdx.x;
  const int w = tid >> 6, l = tid & 63;
  const int g = l >> 4, i = l & 15;
  const int bid = blockIdx.x;
  const int wid = (bid & 7) * 64 + (bid >> 3);
  const int qb = wid & 15;            // S/128 = 16 q-blocks
  const int hb = wid >> 4;
  const int h = hb & 3, b = hb >> 2;
  const size_t base = ((size_t)b * H_ + h) * (size_t)(S_ * D_);

  FragU qf[2];
  #pragma unroll
  for (int qt = 0; qt < 2; ++qt)
    qf[qt].u = *(const uint4*)(qg + base + (size_t)(qb * 128 + w * 32 + qt * 16 + i) * D_ + 8 * g);
  FragU onef;
  onef.u = (uint4){0x3F803F80u, 0x3F803F80u, 0x3F803F80u, 0x3F803F80u};  // bf16 1.0 x8

  // staging: 2 chunks/thread/tensor. K: [128 rows][4x16B]; V: [32 d][16x16B]
  const int kr0 = tid >> 2, kc = tid & 3;
  const int vr0 = tid >> 4, vc = tid & 15;
  const uint4* kp = (const uint4*)(kg + base);
  const unsigned short* vt = vg + base;   // [d][S] slot-permuted

  f32x4 oac[2][2] = {{{0.f,0.f,0.f,0.f},{0.f,0.f,0.f,0.f}},
                     {{0.f,0.f,0.f,0.f},{0.f,0.f,0.f,0.f}}};
  f32x4 sac[2] = {{0.f,0.f,0.f,0.f},{0.f,0.f,0.f,0.f}};

  // prologue: stage tile 0 (128 keys) into buffer 0
  *(uint4*)&Kls[0][kr0][kc * 8]      = kp[kr0 * 4 + kc];
  *(uint4*)&Kls[0][kr0 + 64][kc * 8] = kp[(kr0 + 64) * 4 + kc];
  *(uint4*)&Vt[0][vr0][vc * 8]       = *(const uint4*)(vt + (size_t)vr0 * S_ + vc * 8);
  *(uint4*)&Vt[0][vr0 + 16][vc * 8]  = *(const uint4*)(vt + (size_t)(vr0 + 16) * S_ + vc * 8);

  for (int kt = 0; kt < 16; ++kt) {
    const int cur = kt & 1;
    __syncthreads();   // buf[cur] staged & visible; prior reads of buf[cur^1] done
    uint4 nk0, nk1, nv0, nv1;
    const bool pf = kt < 15;
    if (pf) {
      nk0 = kp[((kt + 1) * 128 + kr0) * 4 + kc];
      nk1 = kp[((kt + 1) * 128 + kr0 + 64) * 4 + kc];
      nv0 = *(const uint4*)(vt + (size_t)vr0 * S_ + (kt + 1) * 128 + vc * 8);
      nv1 = *(const uint4*)(vt + (size_t)(vr0 + 16) * S_ + (kt + 1) * 128 + vc * 8);
    }
    #pragma unroll
    for (int sub = 0; sub < 2; ++sub) {
      // shared K/V fragments for this 64-key sub-tile
      FragU kf[4], vf[4];
      #pragma unroll
      for (int n = 0; n < 4; ++n) kf[n].u = *(const uint4*)&Kls[cur][sub * 64 + n * 16 + i][8 * g];
      #pragma unroll
      for (int n = 0; n < 2; ++n) {
        vf[n].u     = *(const uint4*)&Vt[cur][n * 16 + i][sub * 64 + 8 * g];
        vf[2 + n].u = *(const uint4*)&Vt[cur][n * 16 + i][sub * 64 + 32 + 8 * g];
      }
      #pragma unroll
      for (int qt = 0; qt < 2; ++qt) {
        // ---- QK^T swapped: S[key][q], 4 MFMAs ----
        f32x4 sf[4];
        __builtin_amdgcn_s_setprio(1);
        #pragma unroll
        for (int n = 0; n < 4; ++n) {
          f32x4 z = {0.f, 0.f, 0.f, 0.f};
          sf[n] = __builtin_amdgcn_mfma_f32_16x16x32_bf16(kf[n].h, qf[qt].h, z, 0, 0, 0);
        }
        __builtin_amdgcn_s_setprio(0);
        // ---- p = exp2(s), v_perm truncation-pack into PV A-frags ----
        FragU pa0, pa1;
        pa0.u = (uint4){pk2t(EXP2(sf[0][0]), EXP2(sf[0][1])),
                        pk2t(EXP2(sf[0][2]), EXP2(sf[0][3])),
                        pk2t(EXP2(sf[1][0]), EXP2(sf[1][1])),
                        pk2t(EXP2(sf[1][2]), EXP2(sf[1][3]))};
        pa1.u = (uint4){pk2t(EXP2(sf[2][0]), EXP2(sf[2][1])),
                        pk2t(EXP2(sf[2][2]), EXP2(sf[2][3])),
                        pk2t(EXP2(sf[3][0]), EXP2(sf[3][1])),
                        pk2t(EXP2(sf[3][2]), EXP2(sf[3][3]))};
        // ---- PV + rowsum ----
        __builtin_amdgcn_s_setprio(1);
        sac[qt] = __builtin_amdgcn_mfma_f32_16x16x32_bf16(pa0.h, onef.h, sac[qt], 0, 0, 0);
        oac[qt][0] = __builtin_amdgcn_mfma_f32_16x16x32_bf16(pa0.h, vf[0].h, oac[qt][0], 0, 0, 0);
        oac[qt][1] = __builtin_amdgcn_mfma_f32_16x16x32_bf16(pa0.h, vf[1].h, oac[qt][1], 0, 0, 0);
        sac[qt] = __builtin_amdgcn_mfma_f32_16x16x32_bf16(pa1.h, onef.h, sac[qt], 0, 0, 0);
        oac[qt][0] = __builtin_amdgcn_mfma_f32_16x16x32_bf16(pa1.h, vf[2].h, oac[qt][0], 0, 0, 0);
        oac[qt][1] = __builtin_amdgcn_mfma_f32_16x16x32_bf16(pa1.h, vf[3].h, oac[qt][1], 0, 0, 0);
        __builtin_amdgcn_s_setprio(0);
      }
    }
    // ---- write next tile into the other buffer ----
    if (pf) {
      *(uint4*)&Kls[cur ^ 1][kr0][kc * 8]      = nk0;
      *(uint4*)&Kls[cur ^ 1][kr0 + 64][kc * 8] = nk1;
      *(uint4*)&Vt[cur ^ 1][vr0][vc * 8]       = nv0;
      *(uint4*)&Vt[cur ^ 1][vr0 + 16][vc * 8]  = nv1;
    }
  }
  // normalize + store: rows q = qt*16 + 4g + r, cols d = n*16+i
  #pragma unroll
  for (int qt = 0; qt < 2; ++qt) {
    #pragma unroll
    for (int n = 0; n < 2; ++n) {
      #pragma unroll
      for (int r = 0; r < 4; ++r) {
        size_t row = (size_t)qb * 128 + w * 32 + qt * 16 + 4 * g + r;
        og[((size_t)b * S_ + row) * HD_ + h * D_ + n * 16 + i] = f2bf(oac[qt][n][r] / sac[qt][r]);
      }
    }
  }
}

// ---------- K4: output projection + bias + residual; no LDS, no barriers ----------
__global__ __launch_bounds__(512) void k_out(const unsigned short* __restrict__ o,
                                             const unsigned short* __restrict__ wo_bf,
                                             const float* __restrict__ bo,
                                             const float* __restrict__ x,
                                             float* __restrict__ out) {
  const int tid = threadIdx.x;
  const int w = tid >> 6, l = tid & 63, g = l >> 4, i = l & 15;
  const int gr0 = blockIdx.x * 32;
  const int c = w * 16 + i;
  f32x4 acc[2] = {{0,0,0,0},{0,0,0,0}};
  #pragma unroll
  for (int kk = 0; kk < 4; ++kk) {
    FragU bfr;
    bfr.u = *(const uint4*)(wo_bf + (size_t)c * HD_ + kk * 32 + 8 * g);
    #pragma unroll
    for (int rt = 0; rt < 2; ++rt) {
      FragU af;
      af.u = *(const uint4*)(o + (size_t)(gr0 + rt * 16 + i) * HD_ + kk * 32 + 8 * g);
      acc[rt] = __builtin_amdgcn_mfma_f32_16x16x32_bf16(af.h, bfr.h, acc[rt], 0, 0, 0);
    }
  }
  float bias = bo[c];
  #pragma unroll
  for (int rt = 0; rt < 2; ++rt) {
    #pragma unroll
    for (int r = 0; r < 4; ++r) {
      size_t idx = (size_t)(gr0 + rt * 16 + 4 * g + r) * C_ + c;
      out[idx] = acc[rt][r] + bias + x[idx];
    }
  }
}

extern "C" void kernel_launch(void* const* d_in, const int* in_sizes, int n_in,
                              void* d_out, int out_size, void* d_ws, size_t ws_size,
                              hipStream_t stream) {
  const float* x     = (const float*)d_in[0];
  const float* gamma = (const float*)d_in[1];
  const float* beta  = (const float*)d_in[2];
  const float* wqkv  = (const float*)d_in[3];
  const float* wout  = (const float*)d_in[4];
  const float* bout  = (const float*)d_in[5];
  float* out = (float*)d_out;

  // workspace layout
  float* part  = (float*)((char*)d_ws + 64);                     // 512 floats
  unsigned short* wq_bf = (unsigned short*)((char*)d_ws + 4096); // 49152 bf16
  unsigned short* wo_bf = wq_bf + 49152;                         // 16384 bf16
  unsigned short* q_ws = (unsigned short*)((char*)d_ws + 4096 + 98304 + 32768);
  const size_t per = (size_t)B_ * H_ * S_ * D_;                  // 2,097,152 elements (bf16)
  unsigned short* k_ws = q_ws + per;
  unsigned short* v_ws = k_ws + per;                             // [b][h][d][S] slot-permuted
  unsigned short* o_ws = v_ws + per;                             // [B][S][H*D] bf16

  hipLaunchKernelGGL(k_stats1, dim3(256), dim3(256), 0, stream, x, wqkv, wout, part, wq_bf, wo_bf);
  hipLaunchKernelGGL(k_qkv, dim3(512), dim3(512), 0, stream,
                     x, gamma, beta, wq_bf, part, q_ws, k_ws, v_ws);
  hipLaunchKernelGGL(k_attn, dim3(512), dim3(256), 0, stream,
                     q_ws, k_ws, v_ws, o_ws);
  hipLaunchKernelGGL(k_out, dim3(512), dim3(512), 0, stream,
                     o_ws, wo_bf, bout, x, out);
}

// Round 19
// 53.176 us; speedup vs baseline: 1.1594x; 1.1594x over previous
//
#include <hip/hip_runtime.h>
#include <hip/hip_bf16.h>

// Problem dims
#define B_ 8
#define S_ 2048
#define C_ 128
#define H_ 4
#define D_ 32
#define SC_ (S_*C_)      // 262144 elements per batch
#define HD_ (H_*D_)      // 128

typedef short bf16x8 __attribute__((ext_vector_type(8)));
typedef float f32x4 __attribute__((ext_vector_type(4)));
union FragU { uint4 u; bf16x8 h; };

// ---------- bf16 helpers ----------
__device__ __forceinline__ unsigned short f2bf(float f) {
  __hip_bfloat16 h = __float2bfloat16(f);   // RNE
  return *reinterpret_cast<unsigned short*>(&h);
}
// truncation pack via byte-perm: {hi16(b), hi16(a)} in ONE v_perm_b32.
// P>0 and the SAME values feed numerator and denominator -> bias cancels.
__device__ __forceinline__ unsigned int pk2t(float a, float b) {
  union { float f; unsigned int u; } ua, ub;
  ua.f = a; ub.f = b;
  return __builtin_amdgcn_perm(ub.u, ua.u, 0x07060302u);
}
// RNE pack (for V staging - bias must not accumulate in PV numerator)
__device__ __forceinline__ unsigned int pk2r(float a, float b) {
  return (unsigned int)f2bf(a) | ((unsigned int)f2bf(b) << 16);
}
#define EXP2(x) __builtin_amdgcn_exp2f(x)

// ---------- K1a: GroupNorm partial sums (256 blocks = 8b x 32 slices) + W->bf16 convert ----------
__global__ __launch_bounds__(256) void k_stats1(const float* __restrict__ x,
                                                const float* __restrict__ wqkv,
                                                const float* __restrict__ wout,
                                                float* __restrict__ part,
                                                unsigned short* __restrict__ wq_bf,
                                                unsigned short* __restrict__ wo_bf) {
  __shared__ float ssum[256], ssq[256];
  int b = blockIdx.x >> 5, sl = blockIdx.x & 31;
  int tid = threadIdx.x;
  // fused one-time weight conversion: 16384 float4 total
  int gid = blockIdx.x * 256 + tid;
  if (gid < 16384) {
    int e = gid * 4;
    const float4 u = (e < 49152) ? *(const float4*)(wqkv + e) : *(const float4*)(wout + e - 49152);
    unsigned short tv[4] = {f2bf(u.x), f2bf(u.y), f2bf(u.z), f2bf(u.w)};
    unsigned short* dst = (e < 49152) ? (wq_bf + e) : (wo_bf + e - 49152);
    *(uint2*)dst = *(uint2*)tv;
  }
  const float4* xp = (const float4*)(x + (size_t)b * SC_);   // 65536 float4 per batch
  float sum = 0.f, sq = 0.f;
  for (int i = sl * 2048 + tid; i < (sl + 1) * 2048; i += 256) {
    float4 u = xp[i];
    sum += u.x + u.y + u.z + u.w;
    sq  += u.x*u.x + u.y*u.y + u.z*u.z + u.w*u.w;
  }
  ssum[tid] = sum; ssq[tid] = sq;
  __syncthreads();
  for (int s = 128; s > 0; s >>= 1) {
    if (tid < s) { ssum[tid] += ssum[tid + s]; ssq[tid] += ssq[tid + s]; }
    __syncthreads();
  }
  if (tid == 0) { part[blockIdx.x * 2] = ssum[0]; part[blockIdx.x * 2 + 1] = ssq[0]; }
}

// ---------- K2: normalize + QKV projection, MFMA; W direct from L2; coalesced V epilogue ----------
__global__ __launch_bounds__(512) void k_qkv(const float* __restrict__ x,
                                             const float* __restrict__ gamma,
                                             const float* __restrict__ beta,
                                             const unsigned short* __restrict__ wq_bf,
                                             const float* __restrict__ part,
                                             unsigned short* __restrict__ q_ws,
                                             unsigned short* __restrict__ k_ws,
                                             unsigned short* __restrict__ v_ws) {
  __shared__ __align__(16) unsigned short Nls[32][136];   // reused as Vbuf[128][32]
  __shared__ float gs[128], bs[128];
  __shared__ float st2[2];
  const int tid = threadIdx.x;
  const int w = tid >> 6, l = tid & 63, g = l >> 4, i = l & 15;
  const int gr0 = blockIdx.x * 32;          // never crosses batch
  const int b = gr0 >> 11;
  if (tid < 128) { gs[tid] = gamma[tid]; bs[tid] = beta[tid]; }
  if (tid < 32) {   // in-block stats reduction
    float s1 = part[(b * 32 + tid) * 2];
    float s2 = part[(b * 32 + tid) * 2 + 1];
    #pragma unroll
    for (int m = 16; m >= 1; m >>= 1) { s1 += __shfl_xor(s1, m); s2 += __shfl_xor(s2, m); }
    if (tid == 0) {
      float mu = s1 / (float)SC_;
      float var = s2 / (float)SC_ - mu * mu;
      st2[0] = mu; st2[1] = rsqrtf(var + 1e-5f);
    }
  }
  __syncthreads();
  const float mu = st2[0], rstd = st2[1];
  {
    const float4* xp = (const float4*)(x + (size_t)gr0 * C_);   // 1024 float4
    #pragma unroll
    for (int t = 0; t < 2; ++t) {
      int e = tid + t * 512;
      float4 u = xp[e];
      int r = e >> 5, c0 = (e & 31) * 4;
      float4 gv = *(const float4*)&gs[c0];
      float4 bv = *(const float4*)&bs[c0];
      unsigned short tv[4] = {
        f2bf((u.x - mu) * rstd * gv.x + bv.x),
        f2bf((u.y - mu) * rstd * gv.y + bv.y),
        f2bf((u.z - mu) * rstd * gv.z + bv.z),
        f2bf((u.w - mu) * rstd * gv.w + bv.w)};
      *(uint2*)&Nls[r][c0] = *(uint2*)tv;
    }
  }
  __syncthreads();
  f32x4 acc[2][3];
  #pragma unroll
  for (int rt = 0; rt < 2; ++rt)
    #pragma unroll
    for (int n = 0; n < 3; ++n) acc[rt][n] = (f32x4){0.f,0.f,0.f,0.f};

  #pragma unroll
  for (int kk = 0; kk < 4; ++kk) {
    FragU bfr[3];
    #pragma unroll
    for (int n = 0; n < 3; ++n)
      bfr[n].u = *(const uint4*)(wq_bf + (size_t)((w * 3 + n) * 16 + i) * 128 + kk * 32 + 8 * g);
    FragU af[2];
    #pragma unroll
    for (int rt = 0; rt < 2; ++rt) af[rt].u = *(const uint4*)&Nls[rt * 16 + i][kk * 32 + 8 * g];
    #pragma unroll
    for (int n = 0; n < 3; ++n)
      #pragma unroll
      for (int rt = 0; rt < 2; ++rt)
        acc[rt][n] = __builtin_amdgcn_mfma_f32_16x16x32_bf16(af[rt].h, bfr[n].h, acc[rt][n], 0, 0, 0);
  }
  __syncthreads();   // Nls reads done -> reuse as Vbuf
  unsigned short (*Vbuf)[32] = (unsigned short(*)[32])&Nls[0][0];   // [fi=f-256][slot 0..31]

  const float SCQ = 0.17677669529663687f * 1.4426950408889634f;  // D^-0.5 * log2(e)
  const int base64 = ((blockIdx.x & 63) >> 1) * 64;   // 64-group base within batch
  const int odd32 = (blockIdx.x & 1) * 32;
  #pragma unroll
  for (int n = 0; n < 3; ++n) {
    int f = (w * 3 + n) * 16 + i;
    int which = f >> 7, fi = f & 127, h = fi >> 5, dd = fi & 31;
    #pragma unroll
    for (int rt = 0; rt < 2; ++rt) {
      if (which == 2) {
        *(unsigned int*)&Vbuf[fi][8 * g + 4 * rt]     = pk2r(acc[rt][n][0], acc[rt][n][1]);
        *(unsigned int*)&Vbuf[fi][8 * g + 4 * rt + 2] = pk2r(acc[rt][n][2], acc[rt][n][3]);
      } else {
        #pragma unroll
        for (int r = 0; r < 4; ++r) {
          int s = (gr0 + rt * 16 + 4 * g + r) & (S_ - 1);
          if (which == 0) {
            q_ws[(((size_t)b * H_ + h) * S_ + s) * D_ + dd] = f2bf(acc[rt][n][r] * SCQ);
          } else {
            k_ws[(((size_t)b * H_ + h) * S_ + s) * D_ + dd] = f2bf(acc[rt][n][r]);
          }
        }
      }
    }
  }
  __syncthreads();
  // cooperative coalesced V store: 128 fi x 32 slots = 512 x 16B
  {
    int fi = tid >> 2, ch = tid & 3;
    int h = fi >> 5, dd = fi & 31;
    uint4 vv = *(const uint4*)&Vbuf[fi][ch * 8];
    *(uint4*)(v_ws + (((size_t)b * H_ + h) * D_ + dd) * S_ + base64 + odd32 + ch * 8) = vv;
  }
}

// ---------- K3: MFMA flash attention; 8 waves, QBLK=128, KVBLK=128 ----------
// grid (S/128, H, B) = 512 blocks x 512 threads = 16 waves/CU = 4 waves/SIMD
// (same TLP as the r17 best, HALF the K/V streaming; K/V LDS tiles shared by 8 waves).
// Wave w owns q rows qb*128 + w*16 .. +15. Staging: 1 chunk/thread/tensor.
// Swapped QK^T, P in-register (v_perm trunc pack), rowsum mfma(P,1), setprio.
__global__ __launch_bounds__(512) void k_attn(const unsigned short* __restrict__ qg,
                                              const unsigned short* __restrict__ kg,
                                              const unsigned short* __restrict__ vg,
                                              unsigned short* __restrict__ og) {
  __shared__ __align__(16) unsigned short Kls[2][128][40];
  __shared__ __align__(16) unsigned short Vt[2][32][136];
  const int tid = threadIdx.x;
  const int w = tid >> 6, l = tid & 63;
  const int g = l >> 4, i = l & 15;
  const int qb = blockIdx.x, h = blockIdx.y, b = blockIdx.z;
  const size_t base = ((size_t)b * H_ + h) * (size_t)(S_ * D_);

  FragU qf;
  qf.u = *(const uint4*)(qg + base + (size_t)(qb * 128 + w * 16 + i) * D_ + 8 * g);
  FragU onef;
  onef.u = (uint4){0x3F803F80u, 0x3F803F80u, 0x3F803F80u, 0x3F803F80u};  // bf16 1.0 x8

  // staging (512 threads): K 128 rows x 4 chunks; V 32 d-rows x 16 chunks
  const int kr = tid >> 2, kc = tid & 3;
  const int vr = tid >> 4, vc = tid & 15;
  const uint4* kp = (const uint4*)(kg + base);
  const unsigned short* vt = vg + base;   // [d][S] slot-permuted

  f32x4 oac[2] = {{0.f,0.f,0.f,0.f},{0.f,0.f,0.f,0.f}};
  f32x4 sac = {0.f,0.f,0.f,0.f};          // row-sum accumulator

  // prologue: stage tile 0 (128 keys) into buffer 0
  *(uint4*)&Kls[0][kr][kc * 8] = kp[kr * 4 + kc];
  *(uint4*)&Vt[0][vr][vc * 8]  = *(const uint4*)(vt + (size_t)vr * S_ + vc * 8);

  for (int kt = 0; kt < 16; ++kt) {
    const int cur = kt & 1;
    __syncthreads();   // buf[cur] staged & visible; prior reads of buf[cur^1] done
    uint4 nk, nv;
    const bool pf = kt < 15;
    if (pf) {
      nk = kp[((kt + 1) * 128 + kr) * 4 + kc];
      nv = *(const uint4*)(vt + (size_t)vr * S_ + (kt + 1) * 128 + vc * 8);
    }
    #pragma unroll
    for (int sub = 0; sub < 2; ++sub) {
      // ---- QK^T swapped: S[key][q], 4 MFMAs (scores in log2 units) ----
      f32x4 sf[4];
      __builtin_amdgcn_s_setprio(1);
      #pragma unroll
      for (int n = 0; n < 4; ++n) {
        FragU kf; kf.u = *(const uint4*)&Kls[cur][sub * 64 + n * 16 + i][8 * g];
        f32x4 z = {0.f, 0.f, 0.f, 0.f};
        sf[n] = __builtin_amdgcn_mfma_f32_16x16x32_bf16(kf.h, qf.h, z, 0, 0, 0);
      }
      __builtin_amdgcn_s_setprio(0);
      // ---- p = exp2(s), v_perm truncation-pack into PV A-frags ----
      FragU pa0, pa1;
      pa0.u = (uint4){pk2t(EXP2(sf[0][0]), EXP2(sf[0][1])),
                      pk2t(EXP2(sf[0][2]), EXP2(sf[0][3])),
                      pk2t(EXP2(sf[1][0]), EXP2(sf[1][1])),
                      pk2t(EXP2(sf[1][2]), EXP2(sf[1][3]))};
      pa1.u = (uint4){pk2t(EXP2(sf[2][0]), EXP2(sf[2][1])),
                      pk2t(EXP2(sf[2][2]), EXP2(sf[2][3])),
                      pk2t(EXP2(sf[3][0]), EXP2(sf[3][1])),
                      pk2t(EXP2(sf[3][2]), EXP2(sf[3][3]))};
      // ---- PV + rowsum: contraction over this sub-tile's 64 slots ----
      __builtin_amdgcn_s_setprio(1);
      sac = __builtin_amdgcn_mfma_f32_16x16x32_bf16(pa0.h, onef.h, sac, 0, 0, 0);
      #pragma unroll
      for (int n = 0; n < 2; ++n) {
        FragU vf; vf.u = *(const uint4*)&Vt[cur][n * 16 + i][sub * 64 + 8 * g];
        oac[n] = __builtin_amdgcn_mfma_f32_16x16x32_bf16(pa0.h, vf.h, oac[n], 0, 0, 0);
      }
      sac = __builtin_amdgcn_mfma_f32_16x16x32_bf16(pa1.h, onef.h, sac, 0, 0, 0);
      #pragma unroll
      for (int n = 0; n < 2; ++n) {
        FragU vf; vf.u = *(const uint4*)&Vt[cur][n * 16 + i][sub * 64 + 32 + 8 * g];
        oac[n] = __builtin_amdgcn_mfma_f32_16x16x32_bf16(pa1.h, vf.h, oac[n], 0, 0, 0);
      }
      __builtin_amdgcn_s_setprio(0);
    }
    // ---- write next tile into the other buffer ----
    if (pf) {
      *(uint4*)&Kls[cur ^ 1][kr][kc * 8] = nk;
      *(uint4*)&Vt[cur ^ 1][vr][vc * 8]  = nv;
    }
  }
  // normalize + store: rows q = 4g+r, cols d = n*16+i
  #pragma unroll
  for (int n = 0; n < 2; ++n) {
    #pragma unroll
    for (int r = 0; r < 4; ++r) {
      size_t row = (size_t)qb * 128 + w * 16 + 4 * g + r;
      og[((size_t)b * S_ + row) * HD_ + h * D_ + n * 16 + i] = f2bf(oac[n][r] / sac[r]);
    }
  }
}

// ---------- K4: output projection + bias + residual; no LDS, no barriers ----------
__global__ __launch_bounds__(512) void k_out(const unsigned short* __restrict__ o,
                                             const unsigned short* __restrict__ wo_bf,
                                             const float* __restrict__ bo,
                                             const float* __restrict__ x,
                                             float* __restrict__ out) {
  const int tid = threadIdx.x;
  const int w = tid >> 6, l = tid & 63, g = l >> 4, i = l & 15;
  const int gr0 = blockIdx.x * 32;
  const int c = w * 16 + i;
  f32x4 acc[2] = {{0,0,0,0},{0,0,0,0}};
  #pragma unroll
  for (int kk = 0; kk < 4; ++kk) {
    FragU bfr;
    bfr.u = *(const uint4*)(wo_bf + (size_t)c * HD_ + kk * 32 + 8 * g);
    #pragma unroll
    for (int rt = 0; rt < 2; ++rt) {
      FragU af;
      af.u = *(const uint4*)(o + (size_t)(gr0 + rt * 16 + i) * HD_ + kk * 32 + 8 * g);
      acc[rt] = __builtin_amdgcn_mfma_f32_16x16x32_bf16(af.h, bfr.h, acc[rt], 0, 0, 0);
    }
  }
  float bias = bo[c];
  #pragma unroll
  for (int rt = 0; rt < 2; ++rt) {
    #pragma unroll
    for (int r = 0; r < 4; ++r) {
      size_t idx = (size_t)(gr0 + rt * 16 + 4 * g + r) * C_ + c;
      out[idx] = acc[rt][r] + bias + x[idx];
    }
  }
}

extern "C" void kernel_launch(void* const* d_in, const int* in_sizes, int n_in,
                              void* d_out, int out_size, void* d_ws, size_t ws_size,
                              hipStream_t stream) {
  const float* x     = (const float*)d_in[0];
  const float* gamma = (const float*)d_in[1];
  const float* beta  = (const float*)d_in[2];
  const float* wqkv  = (const float*)d_in[3];
  const float* wout  = (const float*)d_in[4];
  const float* bout  = (const float*)d_in[5];
  float* out = (float*)d_out;

  // workspace layout
  float* part  = (float*)((char*)d_ws + 64);                     // 512 floats
  unsigned short* wq_bf = (unsigned short*)((char*)d_ws + 4096); // 49152 bf16
  unsigned short* wo_bf = wq_bf + 49152;                         // 16384 bf16
  unsigned short* q_ws = (unsigned short*)((char*)d_ws + 4096 + 98304 + 32768);
  const size_t per = (size_t)B_ * H_ * S_ * D_;                  // 2,097,152 elements (bf16)
  unsigned short* k_ws = q_ws + per;
  unsigned short* v_ws = k_ws + per;                             // [b][h][d][S] slot-permuted
  unsigned short* o_ws = v_ws + per;                             // [B][S][H*D] bf16

  hipLaunchKernelGGL(k_stats1, dim3(256), dim3(256), 0, stream, x, wqkv, wout, part, wq_bf, wo_bf);
  hipLaunchKernelGGL(k_qkv, dim3(512), dim3(512), 0, stream,
                     x, gamma, beta, wq_bf, part, q_ws, k_ws, v_ws);
  hipLaunchKernelGGL(k_attn, dim3(S_ / 128, H_, B_), dim3(512), 0, stream,
                     q_ws, k_ws, v_ws, o_ws);
  hipLaunchKernelGGL(k_out, dim3(512), dim3(512), 0, stream,
                     o_ws, wo_bf, bout, x, out);
}